// Round 1
// baseline (1201.001 us; speedup 1.0000x reference)
//
#include <hip/hip_runtime.h>
#include <math.h>

typedef unsigned int u32;
typedef unsigned short u16;
typedef __bf16 bf16x8 __attribute__((ext_vector_type(8)));
typedef float f32x4 __attribute__((ext_vector_type(4)));

#define LL 9216
#define WIN 144
#define NBK 64

__device__ __forceinline__ u16 f2bf(float f){
  union { float f; u32 u; } v; v.f = f;
  u32 u = v.u;
  return (u16)((u + 0x7fffu + ((u >> 16) & 1u)) >> 16);
}
__device__ __forceinline__ float bf2f(u16 b){
  union { u32 u; float f; } v; v.u = ((u32)b) << 16;
  return v.f;
}
__device__ __forceinline__ f32x4 mfma16(bf16x8 a, bf16x8 b, f32x4 c){
  return __builtin_amdgcn_mfma_f32_16x16x32_bf16(a, b, c, 0, 0, 0);
}

// ---------------- prep: weight / means transposes ----------------
__global__ void __launch_bounds__(256) k_prep(const float* __restrict__ wm,
    const float* __restrict__ means, float* __restrict__ WMT, float* __restrict__ MT){
  int i = blockIdx.x * 256 + threadIdx.x;
  if (i < 9*256*64){
    int tap = i / (256*64); int r = i % (256*64); int ci = r >> 6; int o = r & 63;
    WMT[i] = wm[(o*256 + ci)*9 + tap];
  }
  int j = i - 9*256*64;
  if (j >= 0 && j < 64*128){
    int d = j >> 7, cl = j & 127;
    MT[j] = means[cl*64 + d];
  }
}

// ---------------- conv3x3 -> x_embed (fp32, NLC layout) ----------------
__global__ void __launch_bounds__(256) k_conv3(const float* __restrict__ x,
    const float* __restrict__ WMT, const float* __restrict__ bm, float* __restrict__ XE){
  __shared__ float As[16][2][100];
  __shared__ float Ws[16][3][64];
  int n = blockIdx.y;
  int l0 = blockIdx.x * 128;
  int t = threadIdx.x;
  int h0 = l0 / 96;
  int rowsplit = (h0 + 1) * 96 - l0;
  int pg = t & 15, og = t >> 4;
  int o0 = og * 4;
  int r_i[8], w_i[8];
  #pragma unroll
  for (int i = 0; i < 8; i++){
    int p = pg + 16*i;
    int r = (p >= rowsplit) ? 1 : 0;
    r_i[i] = r;
    w_i[i] = l0 + p - (h0 + r) * 96;
  }
  float4 bias = *(const float4*)&bm[o0];
  float acc[8][4];
  #pragma unroll
  for (int i = 0; i < 8; i++){ acc[i][0]=bias.x; acc[i][1]=bias.y; acc[i][2]=bias.z; acc[i][3]=bias.w; }
  for (int ky = 0; ky < 3; ky++){
    for (int cc = 0; cc < 256; cc += 16){
      __syncthreads();
      for (int e = t; e < 16*2*98; e += 256){
        int c = e / 196, rm = e % 196;
        int r = rm / 98, cp = rm % 98;
        int hs = h0 + r + ky - 1;
        int wsrc = cp - 1;
        float v = 0.f;
        if ((u32)hs < 96u && (u32)wsrc < 96u)
          v = x[((size_t)(n*256 + cc + c))*9216 + hs*96 + wsrc];
        As[c][r][cp] = v;
      }
      for (int e = t; e < 16*3*64; e += 256){
        int c = e / 192, rm = e % 192;
        int kx = rm >> 6, o = rm & 63;
        Ws[c][kx][o] = WMT[((size_t)((ky*3 + kx)*256 + cc + c))*64 + o];
      }
      __syncthreads();
      #pragma unroll 4
      for (int k = 0; k < 16; k++){
        float4 w0 = *(const float4*)&Ws[k][0][o0];
        float4 w1 = *(const float4*)&Ws[k][1][o0];
        float4 w2 = *(const float4*)&Ws[k][2][o0];
        #pragma unroll
        for (int i = 0; i < 8; i++){
          const float* ar = &As[k][r_i[i]][w_i[i]];
          float a0 = ar[0], a1 = ar[1], a2 = ar[2];
          acc[i][0] += a0*w0.x + a1*w1.x + a2*w2.x;
          acc[i][1] += a0*w0.y + a1*w1.y + a2*w2.y;
          acc[i][2] += a0*w0.z + a1*w1.z + a2*w2.z;
          acc[i][3] += a0*w0.w + a1*w1.w + a2*w2.w;
        }
      }
    }
  }
  #pragma unroll
  for (int i = 0; i < 8; i++){
    int p = pg + 16*i;
    float4 st; st.x = acc[i][0]; st.y = acc[i][1]; st.z = acc[i][2]; st.w = acc[i][3];
    *(float4*)&XE[((size_t)(n*9216 + l0 + p))*64 + o0] = st;
  }
}

// ---------------- dists + argmax -> codes ----------------
__global__ void __launch_bounds__(256) k_dist(const float* __restrict__ XE,
    const float* __restrict__ MT, u32* __restrict__ CODE){
  __shared__ float ms[64][132];
  __shared__ float xsm[64][65];
  __shared__ float redv[64][16];
  __shared__ int  redi[64][16];
  int n = blockIdx.y, l0 = blockIdx.x * 64;
  int t = threadIdx.x;
  for (int e = t; e < 8192; e += 256) ms[e >> 7][e & 127] = MT[e];
  for (int e = t; e < 4096; e += 256)
    xsm[e >> 6][e & 63] = XE[((size_t)(n*9216 + l0 + (e >> 6)))*64 + (e & 63)];
  __syncthreads();
  int pg = t >> 4, cg = t & 15;
  int p0 = pg * 4, cl0 = cg * 8;
  float acc[4][8];
  #pragma unroll
  for (int i = 0; i < 4; i++)
    #pragma unroll
    for (int j = 0; j < 8; j++) acc[i][j] = 0.f;
  for (int d = 0; d < 64; d++){
    float4 m0 = *(const float4*)&ms[d][cl0];
    float4 m1 = *(const float4*)&ms[d][cl0 + 4];
    #pragma unroll
    for (int i = 0; i < 4; i++){
      float xv = xsm[p0 + i][d];
      acc[i][0] += xv * m0.x; acc[i][1] += xv * m0.y;
      acc[i][2] += xv * m0.z; acc[i][3] += xv * m0.w;
      acc[i][4] += xv * m1.x; acc[i][5] += xv * m1.y;
      acc[i][6] += xv * m1.z; acc[i][7] += xv * m1.w;
    }
  }
  #pragma unroll
  for (int i = 0; i < 4; i++){
    float bv = acc[i][0]; int bi = cl0;
    #pragma unroll
    for (int j = 1; j < 8; j++){ if (acc[i][j] > bv){ bv = acc[i][j]; bi = cl0 + j; } }
    redv[p0 + i][cg] = bv; redi[p0 + i][cg] = bi;
  }
  __syncthreads();
  if (t < 64){
    float bv = redv[t][0]; int bi = redi[t][0];
    for (int c = 1; c < 16; c++){
      float v = redv[t][c];
      if (v > bv){ bv = v; bi = redi[t][c]; }
    }
    CODE[n*9216 + l0 + t] = (u32)bi;
  }
}

// ---------------- stable counting sort per batch ----------------
__global__ void __launch_bounds__(256) k_sort(const u32* __restrict__ CODE,
    u32* __restrict__ IDX, u32* __restrict__ POS){
  __shared__ u32 hist[36][128];
  __shared__ u32 tot[128];
  __shared__ u32 whist[4][128];
  int n = blockIdx.x, t = threadIdx.x;
  for (int e = t; e < 36*128; e += 256) ((u32*)hist)[e] = 0;
  __syncthreads();
  for (int ch = 0; ch < 36; ch++){
    u32 c = CODE[n*9216 + ch*256 + t];
    atomicAdd(&hist[ch][c], 1u);
  }
  __syncthreads();
  if (t < 128){
    u32 run = 0;
    for (int ch = 0; ch < 36; ch++){ u32 v = hist[ch][t]; hist[ch][t] = run; run += v; }
    tot[t] = run;
  }
  __syncthreads();
  if (t == 0){
    u32 base = 0;
    for (int b = 0; b < 128; b++){ u32 v = tot[b]; tot[b] = base; base += v; }
  }
  __syncthreads();
  int wave = t >> 6, lane = t & 63;
  for (int ch = 0; ch < 36; ch++){
    for (int e = t; e < 512; e += 256) ((u32*)whist)[e] = 0;
    __syncthreads();
    int c = (int)CODE[n*9216 + ch*256 + t];
    atomicAdd(&whist[wave][c], 1u);
    __syncthreads();
    u32 pre = 0;
    for (int w2 = 0; w2 < wave; w2++) pre += whist[w2][c];
    u32 cnt = 0;
    for (int j = 0; j < 64; j++){
      int cj = __shfl(c, j, 64);
      cnt += (u32)((j < lane) && (cj == c));
    }
    u32 p = tot[c] + hist[ch][c] + pre + cnt;
    int l = ch*256 + t;
    IDX[n*9216 + p] = (u32)l;
    POS[n*9216 + l] = p;
    __syncthreads();
  }
}

// ---------------- conv1x1 (bf16 MFMA) scattered to sorted YS ----------------
__global__ void __launch_bounds__(256) k_conv1(const float* __restrict__ x,
    const float* __restrict__ wa, const float* __restrict__ ba,
    const u32* __restrict__ POS, u16* __restrict__ YS){
  __shared__ u16 As[64][40];
  __shared__ u16 Bs[256][40];
  __shared__ u16 rl[64][264];
  __shared__ u32 posl[64];
  int n = blockIdx.y, l0 = blockIdx.x * 64;
  int t = threadIdx.x;
  int wave = t >> 6, lane = t & 63, row = lane & 15, kg = lane >> 4;
  if (t < 64) posl[t] = POS[n*9216 + l0 + t];
  f32x4 acc[4][4];
  #pragma unroll
  for (int a = 0; a < 4; a++)
    #pragma unroll
    for (int b = 0; b < 4; b++){ acc[a][b][0]=0.f; acc[a][b][1]=0.f; acc[a][b][2]=0.f; acc[a][b][3]=0.f; }
  for (int ks = 0; ks < 8; ks++){
    int k0 = ks * 32;
    __syncthreads();
    for (int e = t; e < 64*32; e += 256){
      int ci = e >> 6, l = e & 63;
      As[l][ci] = f2bf(x[((size_t)(n*256 + k0 + ci))*9216 + l0 + l]);
    }
    for (int e = t; e < 256*32; e += 256){
      int co = e >> 5, ci = e & 31;
      Bs[co][ci] = f2bf(wa[co*256 + k0 + ci]);
    }
    __syncthreads();
    bf16x8 af[4], bfr[4];
    #pragma unroll
    for (int mt = 0; mt < 4; mt++) af[mt] = *(const bf16x8*)&As[mt*16 + row][kg*8];
    #pragma unroll
    for (int nt = 0; nt < 4; nt++) bfr[nt] = *(const bf16x8*)&Bs[wave*64 + nt*16 + row][kg*8];
    #pragma unroll
    for (int nt = 0; nt < 4; nt++)
      #pragma unroll
      for (int mt = 0; mt < 4; mt++)
        acc[mt][nt] = mfma16(af[mt], bfr[nt], acc[mt][nt]);
  }
  #pragma unroll
  for (int nt = 0; nt < 4; nt++){
    int co = wave*64 + nt*16 + row;
    float bb = ba[co];
    #pragma unroll
    for (int mt = 0; mt < 4; mt++)
      #pragma unroll
      for (int r = 0; r < 4; r++)
        rl[mt*16 + kg*4 + r][co] = f2bf(acc[mt][nt][r] + bb);
  }
  __syncthreads();
  for (int q = t; q < 64*32; q += 256){
    int r = q >> 5, part = q & 31;
    uint4 v = *(const uint4*)&rl[r][part*8];
    *(uint4*)&YS[((size_t)(n*9216 + (int)posl[r]))*256 + part*8] = v;
  }
}

// ---------------- gather x rows into sorted order (+normalized copy) ----------------
__global__ void __launch_bounds__(256) k_gx(const float* __restrict__ XE,
    const u32* __restrict__ IDX, u16* __restrict__ XSU, u16* __restrict__ XSN){
  int gr = blockIdx.x * 4 + (threadIdx.x >> 6);
  int lane = threadIdx.x & 63;
  int n = gr / 9216;
  int l = (int)IDX[gr];
  float v = XE[((size_t)(n*9216 + l))*64 + lane];
  float s = v * v;
  #pragma unroll
  for (int m = 1; m < 64; m <<= 1) s += __shfl_xor(s, m, 64);
  float scale = 1.f / fmaxf(sqrtf(s), 5e-5f);
  XSU[(size_t)gr*64 + lane] = f2bf(v);
  XSN[(size_t)gr*64 + lane] = f2bf(v * scale);
}

// ---------------- attention per (n, window) ----------------
#define PL_STRIDE 456
#define SM_YLDS (144*456*2)
#define YL_STRIDE 20
#define SM_IDXL (SM_YLDS + 256*YL_STRIDE*4)
#define SM_ATTN (SM_IDXL + 144*4)

__global__ void __launch_bounds__(256, 1) k_attn(const u16* __restrict__ XSU,
    const u16* __restrict__ XSN, const u16* __restrict__ YS,
    const u32* __restrict__ IDX, u16* __restrict__ RET){
  extern __shared__ char smem[];
  u16* Plds = (u16*)smem;
  u32* Ylds = (u32*)(smem + SM_YLDS);
  u32* idxl = (u32*)(smem + SM_IDXL);
  int n = blockIdx.y, kw = blockIdx.x;
  int t = threadIdx.x;
  int wave = t >> 6, lane = t & 63;
  int row = lane & 15, kg = lane >> 4;
  int p0 = kw * WIN;
  if (t < WIN) idxl[t] = IDX[n*LL + p0 + t];
  int wprev = (kw + NBK - 1) & (NBK - 1), wnext = (kw + 1) & (NBK - 1);
  int segbase[3] = { p0, wprev*WIN, wnext*WIN };
  // S = xb @ x_match^T   (store raw logits bf16 to Plds)
  {
    bf16x8 a[9][2];
    #pragma unroll
    for (int mt = 0; mt < 9; mt++){
      const u16* xp = XSU + ((size_t)(n*LL + p0 + mt*16 + row))*64 + kg*8;
      a[mt][0] = *(const bf16x8*)xp;
      a[mt][1] = *(const bf16x8*)(xp + 32);
    }
    for (int jt = wave; jt < 27; jt += 4){
      int j0 = jt * 16;
      int seg = j0 / WIN;
      int sp = segbase[seg] + (j0 - seg*WIN) + row;
      const u16* bp = XSN + ((size_t)(n*LL + sp))*64 + kg*8;
      bf16x8 b0 = *(const bf16x8*)bp;
      bf16x8 b1 = *(const bf16x8*)(bp + 32);
      #pragma unroll
      for (int mt = 0; mt < 9; mt++){
        f32x4 s; s[0]=0.f; s[1]=0.f; s[2]=0.f; s[3]=0.f;
        s = mfma16(a[mt][0], b0, s);
        s = mfma16(a[mt][1], b1, s);
        #pragma unroll
        for (int r = 0; r < 4; r++)
          Plds[(mt*16 + kg*4 + r)*PL_STRIDE + j0 + row] = f2bf(s[r]);
      }
    }
  }
  __syncthreads();
  // exact softmax per row (16 threads per row)
  for (int pass = 0; pass < 9; pass++){
    int rr = pass*16 + (t >> 4);
    int tc = t & 15;
    u16* prow = Plds + rr*PL_STRIDE;
    float vals[27]; float mx = -1e30f;
    #pragma unroll
    for (int jj = 0; jj < 27; jj++){ vals[jj] = bf2f(prow[tc + 16*jj]); mx = fmaxf(mx, vals[jj]); }
    mx = fmaxf(mx, __shfl_xor(mx, 1, 64));
    mx = fmaxf(mx, __shfl_xor(mx, 2, 64));
    mx = fmaxf(mx, __shfl_xor(mx, 4, 64));
    mx = fmaxf(mx, __shfl_xor(mx, 8, 64));
    float sum = 0.f;
    #pragma unroll
    for (int jj = 0; jj < 27; jj++){ vals[jj] = __expf(vals[jj] - mx); sum += vals[jj]; }
    sum += __shfl_xor(sum, 1, 64);
    sum += __shfl_xor(sum, 2, 64);
    sum += __shfl_xor(sum, 4, 64);
    sum += __shfl_xor(sum, 8, 64);
    float inv = 1.f / sum;
    #pragma unroll
    for (int jj = 0; jj < 27; jj++) prow[tc + 16*jj] = f2bf(vals[jj] * inv);
    if (tc < 12){ prow[432 + tc] = 0; prow[444 + tc] = 0; }
  }
  __syncthreads();
  // PV: ret = P @ Y3
  f32x4 acc[9][4];
  #pragma unroll
  for (int a = 0; a < 9; a++)
    #pragma unroll
    for (int b = 0; b < 4; b++){ acc[a][b][0]=0.f; acc[a][b][1]=0.f; acc[a][b][2]=0.f; acc[a][b][3]=0.f; }
  for (int ks = 0; ks < 14; ks++){
    int j0 = ks * 32;
    __syncthreads();
    for (int it = t; it < 512; it += 256){
      int q = it & 15;
      int c8 = (it >> 4) * 8;
      int jA = j0 + 2*q;
      if (jA >= 432){
        #pragma unroll
        for (int kk = 0; kk < 8; kk++) Ylds[(c8 + kk)*YL_STRIDE + q] = 0u;
      } else {
        int seg = jA / WIN;
        int spA = segbase[seg] + (jA - seg*WIN);
        const u16* ya = YS + ((size_t)(n*LL + spA))*256 + c8;
        uint4 va = *(const uint4*)ya;
        uint4 vb = *(const uint4*)(ya + 256);
        u32 pa[4] = {va.x, va.y, va.z, va.w};
        u32 pb[4] = {vb.x, vb.y, vb.z, vb.w};
        #pragma unroll
        for (int kk = 0; kk < 4; kk++){
          Ylds[(c8 + 2*kk    )*YL_STRIDE + q] = (pa[kk] & 0xffffu) | (pb[kk] << 16);
          Ylds[(c8 + 2*kk + 1)*YL_STRIDE + q] = (pa[kk] >> 16) | (pb[kk] & 0xffff0000u);
        }
      }
    }
    __syncthreads();
    bf16x8 ap[9];
    #pragma unroll
    for (int mt = 0; mt < 9; mt++)
      ap[mt] = *(const bf16x8*)&Plds[(mt*16 + row)*PL_STRIDE + j0 + kg*8];
    #pragma unroll
    for (int nt = 0; nt < 4; nt++){
      int co = (wave*4 + nt)*16 + row;
      bf16x8 bv = *(const bf16x8*)&Ylds[co*YL_STRIDE + kg*4];
      #pragma unroll
      for (int mt = 0; mt < 9; mt++)
        acc[mt][nt] = mfma16(ap[mt], bv, acc[mt][nt]);
    }
  }
  __syncthreads();
  // epilogue: stage rows, scatter to original positions (undo sort)
  u16* rstage = Plds;  // reuse as [144][264]
  #pragma unroll
  for (int mt = 0; mt < 9; mt++)
    #pragma unroll
    for (int nt = 0; nt < 4; nt++){
      int co = (wave*4 + nt)*16 + row;
      #pragma unroll
      for (int r = 0; r < 4; r++)
        rstage[(mt*16 + kg*4 + r)*264 + co] = f2bf(acc[mt][nt][r]);
    }
  __syncthreads();
  for (int q = t; q < WIN*32; q += 256){
    int rr2 = q >> 5, part = q & 31;
    uint4 v = *(const uint4*)&rstage[rr2*264 + part*8];
    *(uint4*)&RET[((size_t)(n*LL + (int)idxl[rr2]))*256 + part*8] = v;
  }
}

// ---------------- final: out = input + 0.1 * RET^T ----------------
__global__ void __launch_bounds__(256) k_final(const u16* __restrict__ RET,
    const float* __restrict__ x, float* __restrict__ out){
  __shared__ u16 tl[64][72];
  int n = blockIdx.z, cb = blockIdx.y * 64, l0 = blockIdx.x * 64;
  int t = threadIdx.x;
  for (int it = t; it < 512; it += 256){
    int r = it >> 3, part = it & 7;
    uint4 v = *(const uint4*)&RET[((size_t)(n*9216 + l0 + r))*256 + cb + part*8];
    *(uint4*)&tl[r][part*8] = v;
  }
  __syncthreads();
  int col = t >> 2, lq = (t & 3) * 16;
  int co = cb + col;
  const float* xin = x + ((size_t)(n*256 + co))*9216 + l0 + lq;
  float* op = out + ((size_t)(n*256 + co))*9216 + l0 + lq;
  #pragma unroll
  for (int i4 = 0; i4 < 4; i4++){
    float4 o4;
    o4.x = fmaf(bf2f(tl[lq + i4*4 + 0][col]), 0.1f, xin[i4*4 + 0]);
    o4.y = fmaf(bf2f(tl[lq + i4*4 + 1][col]), 0.1f, xin[i4*4 + 1]);
    o4.z = fmaf(bf2f(tl[lq + i4*4 + 2][col]), 0.1f, xin[i4*4 + 2]);
    o4.w = fmaf(bf2f(tl[lq + i4*4 + 3][col]), 0.1f, xin[i4*4 + 3]);
    *(float4*)&op[i4*4] = o4;
  }
}

// ---------------- launcher ----------------
#define SZ_XE   (8ull*9216*64*4)
#define OFF_XE  ((size_t)0)
#define OFF_WMT (OFF_XE + SZ_XE)
#define SZ_WMT  (9ull*256*64*4)
#define OFF_MT  (OFF_WMT + SZ_WMT)
#define SZ_MT   (64ull*128*4)
#define OFF_CODE (OFF_MT + SZ_MT)
#define SZ_CODE (8ull*9216*4)
#define OFF_IDX (OFF_CODE + SZ_CODE)
#define OFF_POS (OFF_IDX + SZ_CODE)
#define OFF_XSU (OFF_POS + SZ_CODE)
#define SZ_XS   (8ull*9216*64*2)
#define OFF_XSN (OFF_XSU + SZ_XS)
#define OFF_YS  (OFF_XSN + SZ_XS)
#define SZ_YS   (8ull*9216*256*2)
#define OFF_RET (OFF_YS + SZ_YS)

extern "C" void kernel_launch(void* const* d_in, const int* in_sizes, int n_in,
                              void* d_out, int out_size, void* d_ws, size_t ws_size,
                              hipStream_t stream){
  const float* x     = (const float*)d_in[0];
  const float* means = (const float*)d_in[1];
  const float* wm    = (const float*)d_in[2];
  const float* bm    = (const float*)d_in[3];
  const float* wa    = (const float*)d_in[4];
  const float* ba    = (const float*)d_in[5];
  float* out = (float*)d_out;
  char* ws = (char*)d_ws;

  float* XE   = (float*)(ws + OFF_XE);
  float* WMT  = (float*)(ws + OFF_WMT);
  float* MT   = (float*)(ws + OFF_MT);
  u32*   CODE = (u32*)(ws + OFF_CODE);
  u32*   IDX  = (u32*)(ws + OFF_IDX);
  u32*   POS  = (u32*)(ws + OFF_POS);
  u16*   XSU  = (u16*)(ws + OFF_XSU);
  u16*   XSN  = (u16*)(ws + OFF_XSN);
  u16*   YS   = (u16*)(ws + OFF_YS);
  u16*   RET  = (u16*)(ws + OFF_RET);

  hipFuncSetAttribute((const void*)k_attn,
                      hipFuncAttributeMaxDynamicSharedMemorySize, SM_ATTN);

  k_prep <<<608, 256, 0, stream>>>(wm, means, WMT, MT);
  k_conv3<<<dim3(72, 8), 256, 0, stream>>>(x, WMT, bm, XE);
  k_dist <<<dim3(144, 8), 256, 0, stream>>>(XE, MT, CODE);
  k_sort <<<8, 256, 0, stream>>>(CODE, IDX, POS);
  k_conv1<<<dim3(144, 8), 256, 0, stream>>>(x, wa, ba, POS, YS);
  k_gx   <<<18432, 256, 0, stream>>>(XE, IDX, XSU, XSN);
  k_attn <<<dim3(64, 8), 256, SM_ATTN, stream>>>(XSU, XSN, YS, IDX, RET);
  k_final<<<dim3(144, 4, 8), 256, 0, stream>>>(RET, x, out);
}

// Round 2
// 578.212 us; speedup vs baseline: 2.0771x; 2.0771x over previous
//
#include <hip/hip_runtime.h>
#include <math.h>

typedef unsigned int u32;
typedef unsigned short u16;
typedef __bf16 bf16x8 __attribute__((ext_vector_type(8)));
typedef _Float16 f16x8 __attribute__((ext_vector_type(8)));
typedef float f32x4 __attribute__((ext_vector_type(4)));

#define LL 9216
#define WIN 144
#define NBK 64

__device__ __forceinline__ u16 f2bf(float f){
  union { float f; u32 u; } v; v.f = f;
  u32 u = v.u;
  return (u16)((u + 0x7fffu + ((u >> 16) & 1u)) >> 16);
}
__device__ __forceinline__ float bf2f(u16 b){
  union { u32 u; float f; } v; v.u = ((u32)b) << 16;
  return v.f;
}
__device__ __forceinline__ u16 f2h(float f){
  union { _Float16 h; u16 u; } v; v.h = (_Float16)f;
  return v.u;
}
__device__ __forceinline__ float h2f(u16 h){
  union { _Float16 h; u16 u; } v; v.u = h;
  return (float)v.h;
}
__device__ __forceinline__ f32x4 mfma16(bf16x8 a, bf16x8 b, f32x4 c){
  return __builtin_amdgcn_mfma_f32_16x16x32_bf16(a, b, c, 0, 0, 0);
}
__device__ __forceinline__ f32x4 mfma16h(f16x8 a, f16x8 b, f32x4 c){
  return __builtin_amdgcn_mfma_f32_16x16x32_f16(a, b, c, 0, 0, 0);
}

// ---------------- prep: weight f16 + means transposes ----------------
// WF16 layout: [tap(9)][cc(8)][o(64)][ci(32)] f16
__global__ void __launch_bounds__(256) k_prep(const float* __restrict__ wm,
    const float* __restrict__ means, u16* __restrict__ WF16, float* __restrict__ MT){
  int i = blockIdx.x * 256 + threadIdx.x;
  if (i < 9*8*64*32){
    int tap = i >> 14;
    int cc  = (i >> 11) & 7;
    int o   = (i >> 5) & 63;
    int chl = i & 31;
    WF16[i] = f2h(wm[(o*256 + cc*32 + chl)*9 + tap]);
  }
  int j = i - 9*8*64*32;
  if (j >= 0 && j < 64*128){
    int d = j >> 7, cl = j & 127;
    MT[j] = means[cl*64 + d];
  }
}

// ---------------- transpose+pad+f16split+swizzle: x -> XTH/XTL ----------------
// XT layout: [n][cc(8)][hh(98)][ww(98)][32] f16, hh=h+1, ww=w+1, borders zero.
// Swizzle: slot s (8-elem group) at [ww] holds channels (s ^ ((ww>>1)&3))*8..+7
__global__ void __launch_bounds__(256) k_xt(const float* __restrict__ x,
    u16* __restrict__ XTH, u16* __restrict__ XTL){
  __shared__ float ls[32][97];
  int hh = blockIdx.x, cc = blockIdx.y, n = blockIdx.z;
  int t = threadIdx.x;
  int h = hh - 1;
  bool interior = (h >= 0 && h < 96);
  if (interior){
    int c = t >> 3, w0 = (t & 7) * 12;
    const float* src = x + ((size_t)(n*256 + cc*32 + c))*9216 + h*96 + w0;
    float4 v0 = *(const float4*)src;
    float4 v1 = *(const float4*)(src + 4);
    float4 v2 = *(const float4*)(src + 8);
    ls[c][w0+0]=v0.x; ls[c][w0+1]=v0.y; ls[c][w0+2]=v0.z; ls[c][w0+3]=v0.w;
    ls[c][w0+4]=v1.x; ls[c][w0+5]=v1.y; ls[c][w0+6]=v1.z; ls[c][w0+7]=v1.w;
    ls[c][w0+8]=v2.x; ls[c][w0+9]=v2.y; ls[c][w0+10]=v2.z; ls[c][w0+11]=v2.w;
  }
  __syncthreads();
  size_t base = ((size_t)((n*8 + cc)*98 + hh))*3136;
  for (int u = t; u < 392; u += 256){
    int ww = u >> 2, s = u & 3;
    int w = ww - 1;
    u16 hbuf[8], lbuf[8];
    if (interior && w >= 0 && w < 96){
      int f = (ww >> 1) & 3;
      int cbase = (s ^ f) * 8;
      #pragma unroll
      for (int j = 0; j < 8; j++){
        float v = ls[cbase + j][w];
        _Float16 hv = (_Float16)v;
        float lres = v - (float)hv;
        union { _Float16 h; u16 u; } uh; uh.h = hv;
        hbuf[j] = uh.u;
        lbuf[j] = f2h(lres);
      }
    } else {
      #pragma unroll
      for (int j = 0; j < 8; j++){ hbuf[j] = 0; lbuf[j] = 0; }
    }
    *(uint4*)&XTH[base + ww*32 + s*8] = *(const uint4*)hbuf;
    *(uint4*)&XTL[base + ww*32 + s*8] = *(const uint4*)lbuf;
  }
}

// ---------------- conv3x3 via MFMA (f16 split-2) -> XE fp32 ----------------
__global__ void __launch_bounds__(256) k_conv3(
    const u16* __restrict__ XTH, const u16* __restrict__ XTL,
    const u16* __restrict__ WF16, const float* __restrict__ bm,
    float* __restrict__ XE){
  __shared__ u16 AH[3*3136];
  __shared__ u16 AL[3*3136];
  int h0 = blockIdx.x, n = blockIdx.y;
  int t = threadIdx.x;
  int wave = t >> 6, lane = t & 63, row = lane & 15, kg = lane >> 4;
  f32x4 acc[6];
  #pragma unroll
  for (int m = 0; m < 6; m++){ acc[m][0]=0.f; acc[m][1]=0.f; acc[m][2]=0.f; acc[m][3]=0.f; }
  for (int cc = 0; cc < 8; cc++){
    __syncthreads();
    const u16* srcH = XTH + ((size_t)((n*8 + cc)*98 + h0))*3136;
    const u16* srcL = XTL + ((size_t)((n*8 + cc)*98 + h0))*3136;
    for (int u = t; u < 1176; u += 256){
      *(uint4*)&AH[u*8] = *(const uint4*)&srcH[u*8];
      *(uint4*)&AL[u*8] = *(const uint4*)&srcL[u*8];
    }
    __syncthreads();
    #pragma unroll
    for (int dy = 0; dy < 3; dy++){
      #pragma unroll
      for (int dx = 0; dx < 3; dx++){
        const u16* wp = WF16 + (((size_t)((dy*3 + dx)*8 + cc)*64) + wave*16 + row)*32 + kg*8;
        f16x8 bfrag = *(const f16x8*)wp;
        #pragma unroll
        for (int mt = 0; mt < 6; mt++){
          int ww = mt*16 + row + dx;
          int sl = (kg ^ ((ww >> 1) & 3)) * 8;
          f16x8 ahi = *(const f16x8*)&AH[dy*3136 + ww*32 + sl];
          f16x8 alo = *(const f16x8*)&AL[dy*3136 + ww*32 + sl];
          acc[mt] = mfma16h(ahi, bfrag, acc[mt]);
          acc[mt] = mfma16h(alo, bfrag, acc[mt]);
        }
      }
    }
  }
  int o = wave*16 + row;
  float bb = bm[o];
  #pragma unroll
  for (int mt = 0; mt < 6; mt++){
    #pragma unroll
    for (int r = 0; r < 4; r++){
      int m = mt*16 + kg*4 + r;
      XE[((size_t)(n*9216 + h0*96 + m))*64 + o] = acc[mt][r] + bb;
    }
  }
}

// ---------------- dists + argmax -> codes ----------------
__global__ void __launch_bounds__(256) k_dist(const float* __restrict__ XE,
    const float* __restrict__ MT, u32* __restrict__ CODE){
  __shared__ float ms[64][132];
  __shared__ float xsm[64][65];
  __shared__ float redv[64][16];
  __shared__ int  redi[64][16];
  int n = blockIdx.y, l0 = blockIdx.x * 64;
  int t = threadIdx.x;
  for (int e = t; e < 8192; e += 256) ms[e >> 7][e & 127] = MT[e];
  for (int e = t; e < 4096; e += 256)
    xsm[e >> 6][e & 63] = XE[((size_t)(n*9216 + l0 + (e >> 6)))*64 + (e & 63)];
  __syncthreads();
  int pg = t >> 4, cg = t & 15;
  int p0 = pg * 4, cl0 = cg * 8;
  float acc[4][8];
  #pragma unroll
  for (int i = 0; i < 4; i++)
    #pragma unroll
    for (int j = 0; j < 8; j++) acc[i][j] = 0.f;
  for (int d = 0; d < 64; d++){
    float4 m0 = *(const float4*)&ms[d][cl0];
    float4 m1 = *(const float4*)&ms[d][cl0 + 4];
    #pragma unroll
    for (int i = 0; i < 4; i++){
      float xv = xsm[p0 + i][d];
      acc[i][0] += xv * m0.x; acc[i][1] += xv * m0.y;
      acc[i][2] += xv * m0.z; acc[i][3] += xv * m0.w;
      acc[i][4] += xv * m1.x; acc[i][5] += xv * m1.y;
      acc[i][6] += xv * m1.z; acc[i][7] += xv * m1.w;
    }
  }
  #pragma unroll
  for (int i = 0; i < 4; i++){
    float bv = acc[i][0]; int bi = cl0;
    #pragma unroll
    for (int j = 1; j < 8; j++){ if (acc[i][j] > bv){ bv = acc[i][j]; bi = cl0 + j; } }
    redv[p0 + i][cg] = bv; redi[p0 + i][cg] = bi;
  }
  __syncthreads();
  if (t < 64){
    float bv = redv[t][0]; int bi = redi[t][0];
    for (int c = 1; c < 16; c++){
      float v = redv[t][c];
      if (v > bv){ bv = v; bi = redi[t][c]; }
    }
    CODE[n*9216 + l0 + t] = (u32)bi;
  }
}

// ---------------- stable counting sort per batch ----------------
__global__ void __launch_bounds__(256) k_sort(const u32* __restrict__ CODE,
    u32* __restrict__ IDX, u32* __restrict__ POS){
  __shared__ u32 hist[36][128];
  __shared__ u32 tot[128];
  __shared__ u32 whist[4][128];
  int n = blockIdx.x, t = threadIdx.x;
  for (int e = t; e < 36*128; e += 256) ((u32*)hist)[e] = 0;
  __syncthreads();
  for (int ch = 0; ch < 36; ch++){
    u32 c = CODE[n*9216 + ch*256 + t];
    atomicAdd(&hist[ch][c], 1u);
  }
  __syncthreads();
  if (t < 128){
    u32 run = 0;
    for (int ch = 0; ch < 36; ch++){ u32 v = hist[ch][t]; hist[ch][t] = run; run += v; }
    tot[t] = run;
  }
  __syncthreads();
  if (t == 0){
    u32 base = 0;
    for (int b = 0; b < 128; b++){ u32 v = tot[b]; tot[b] = base; base += v; }
  }
  __syncthreads();
  int wave = t >> 6, lane = t & 63;
  for (int ch = 0; ch < 36; ch++){
    for (int e = t; e < 512; e += 256) ((u32*)whist)[e] = 0;
    __syncthreads();
    int c = (int)CODE[n*9216 + ch*256 + t];
    atomicAdd(&whist[wave][c], 1u);
    __syncthreads();
    u32 pre = 0;
    for (int w2 = 0; w2 < wave; w2++) pre += whist[w2][c];
    u32 cnt = 0;
    for (int j = 0; j < 64; j++){
      int cj = __shfl(c, j, 64);
      cnt += (u32)((j < lane) && (cj == c));
    }
    u32 p = tot[c] + hist[ch][c] + pre + cnt;
    int l = ch*256 + t;
    IDX[n*9216 + p] = (u32)l;
    POS[n*9216 + l] = p;
    __syncthreads();
  }
}

// ---------------- conv1x1 (bf16 MFMA) scattered to sorted YS ----------------
__global__ void __launch_bounds__(256) k_conv1(const float* __restrict__ x,
    const float* __restrict__ wa, const float* __restrict__ ba,
    const u32* __restrict__ POS, u16* __restrict__ YS){
  __shared__ u16 As[64][40];
  __shared__ u16 Bs[256][40];
  __shared__ u16 rl[64][264];
  __shared__ u32 posl[64];
  int n = blockIdx.y, l0 = blockIdx.x * 64;
  int t = threadIdx.x;
  int wave = t >> 6, lane = t & 63, row = lane & 15, kg = lane >> 4;
  if (t < 64) posl[t] = POS[n*9216 + l0 + t];
  f32x4 acc[4][4];
  #pragma unroll
  for (int a = 0; a < 4; a++)
    #pragma unroll
    for (int b = 0; b < 4; b++){ acc[a][b][0]=0.f; acc[a][b][1]=0.f; acc[a][b][2]=0.f; acc[a][b][3]=0.f; }
  for (int ks = 0; ks < 8; ks++){
    int k0 = ks * 32;
    __syncthreads();
    for (int e = t; e < 64*32; e += 256){
      int ci = e >> 6, l = e & 63;
      As[l][ci] = f2bf(x[((size_t)(n*256 + k0 + ci))*9216 + l0 + l]);
    }
    for (int e = t; e < 256*32; e += 256){
      int co = e >> 5, ci = e & 31;
      Bs[co][ci] = f2bf(wa[co*256 + k0 + ci]);
    }
    __syncthreads();
    bf16x8 af[4], bfr[4];
    #pragma unroll
    for (int mt = 0; mt < 4; mt++) af[mt] = *(const bf16x8*)&As[mt*16 + row][kg*8];
    #pragma unroll
    for (int nt = 0; nt < 4; nt++) bfr[nt] = *(const bf16x8*)&Bs[wave*64 + nt*16 + row][kg*8];
    #pragma unroll
    for (int nt = 0; nt < 4; nt++)
      #pragma unroll
      for (int mt = 0; mt < 4; mt++)
        acc[mt][nt] = mfma16(af[mt], bfr[nt], acc[mt][nt]);
  }
  #pragma unroll
  for (int nt = 0; nt < 4; nt++){
    int co = wave*64 + nt*16 + row;
    float bb = ba[co];
    #pragma unroll
    for (int mt = 0; mt < 4; mt++)
      #pragma unroll
      for (int r = 0; r < 4; r++)
        rl[mt*16 + kg*4 + r][co] = f2bf(acc[mt][nt][r] + bb);
  }
  __syncthreads();
  for (int q = t; q < 64*32; q += 256){
    int r = q >> 5, part = q & 31;
    uint4 v = *(const uint4*)&rl[r][part*8];
    *(uint4*)&YS[((size_t)(n*9216 + (int)posl[r]))*256 + part*8] = v;
  }
}

// ---------------- gather x rows into sorted order (normalized + norm) ----------------
__global__ void __launch_bounds__(256) k_gx(const float* __restrict__ XE,
    const u32* __restrict__ IDX, u16* __restrict__ XSN, float* __restrict__ RNRM){
  int gr = blockIdx.x * 4 + (threadIdx.x >> 6);
  int lane = threadIdx.x & 63;
  int n = gr / 9216;
  int l = (int)IDX[gr];
  float v = XE[((size_t)(n*9216 + l))*64 + lane];
  float s = v * v;
  #pragma unroll
  for (int m = 1; m < 64; m <<= 1) s += __shfl_xor(s, m, 64);
  float denom = fmaxf(sqrtf(s), 5e-5f);
  XSN[(size_t)gr*64 + lane] = f2bf(v / denom);
  if (lane == 0) RNRM[gr] = denom;
}

// ---------------- attention per (n, window) ----------------
#define PL_STRIDE 456
#define SM_YLDS (144*456*2)
#define YL_STRIDE 20
#define SM_IDXL (SM_YLDS + 256*YL_STRIDE*4)
#define SM_ATTN (SM_IDXL + 144*4)

__global__ void __launch_bounds__(256, 1) k_attn(const u16* __restrict__ XSN,
    const u16* __restrict__ YS, const u32* __restrict__ IDX,
    const float* __restrict__ RNRM, u16* __restrict__ RET){
  extern __shared__ char smem[];
  u16* Plds = (u16*)smem;
  u32* Ylds = (u32*)(smem + SM_YLDS);
  u32* idxl = (u32*)(smem + SM_IDXL);
  int n = blockIdx.y, kw = blockIdx.x;
  int t = threadIdx.x;
  int wave = t >> 6, lane = t & 63;
  int row = lane & 15, kg = lane >> 4;
  int p0 = kw * WIN;
  if (t < WIN) idxl[t] = IDX[n*LL + p0 + t];
  int wprev = (kw + NBK - 1) & (NBK - 1), wnext = (kw + 1) & (NBK - 1);
  int segbase[3] = { p0, wprev*WIN, wnext*WIN };
  // S = xb_normalized @ x_match^T   (store unit-scale logits bf16 to Plds)
  {
    bf16x8 a[9][2];
    #pragma unroll
    for (int mt = 0; mt < 9; mt++){
      const u16* xp = XSN + ((size_t)(n*LL + p0 + mt*16 + row))*64 + kg*8;
      a[mt][0] = *(const bf16x8*)xp;
      a[mt][1] = *(const bf16x8*)(xp + 32);
    }
    for (int jt = wave; jt < 27; jt += 4){
      int j0 = jt * 16;
      int seg = j0 / WIN;
      int sp = segbase[seg] + (j0 - seg*WIN) + row;
      const u16* bp = XSN + ((size_t)(n*LL + sp))*64 + kg*8;
      bf16x8 b0 = *(const bf16x8*)bp;
      bf16x8 b1 = *(const bf16x8*)(bp + 32);
      #pragma unroll
      for (int mt = 0; mt < 9; mt++){
        f32x4 s; s[0]=0.f; s[1]=0.f; s[2]=0.f; s[3]=0.f;
        s = mfma16(a[mt][0], b0, s);
        s = mfma16(a[mt][1], b1, s);
        #pragma unroll
        for (int r = 0; r < 4; r++)
          Plds[(mt*16 + kg*4 + r)*PL_STRIDE + j0 + row] = f2bf(s[r]);
      }
    }
  }
  __syncthreads();
  // exact softmax per row (16 threads per row), logits scaled by row norm
  for (int pass = 0; pass < 9; pass++){
    int rr = pass*16 + (t >> 4);
    int tc = t & 15;
    float rn = RNRM[n*LL + p0 + rr];
    u16* prow = Plds + rr*PL_STRIDE;
    float vals[27]; float mx = -1e30f;
    #pragma unroll
    for (int jj = 0; jj < 27; jj++){ vals[jj] = bf2f(prow[tc + 16*jj]) * rn; mx = fmaxf(mx, vals[jj]); }
    mx = fmaxf(mx, __shfl_xor(mx, 1, 64));
    mx = fmaxf(mx, __shfl_xor(mx, 2, 64));
    mx = fmaxf(mx, __shfl_xor(mx, 4, 64));
    mx = fmaxf(mx, __shfl_xor(mx, 8, 64));
    float sum = 0.f;
    #pragma unroll
    for (int jj = 0; jj < 27; jj++){ vals[jj] = __expf(vals[jj] - mx); sum += vals[jj]; }
    sum += __shfl_xor(sum, 1, 64);
    sum += __shfl_xor(sum, 2, 64);
    sum += __shfl_xor(sum, 4, 64);
    sum += __shfl_xor(sum, 8, 64);
    float inv = 1.f / sum;
    #pragma unroll
    for (int jj = 0; jj < 27; jj++) prow[tc + 16*jj] = f2bf(vals[jj] * inv);
    if (tc < 12){ prow[432 + tc] = 0; prow[444 + tc] = 0; }
  }
  __syncthreads();
  // PV: ret = P @ Y3
  f32x4 acc[9][4];
  #pragma unroll
  for (int a = 0; a < 9; a++)
    #pragma unroll
    for (int b = 0; b < 4; b++){ acc[a][b][0]=0.f; acc[a][b][1]=0.f; acc[a][b][2]=0.f; acc[a][b][3]=0.f; }
  for (int ks = 0; ks < 14; ks++){
    int j0 = ks * 32;
    __syncthreads();
    for (int it = t; it < 512; it += 256){
      int q = it & 15;
      int c8 = (it >> 4) * 8;
      int jA = j0 + 2*q;
      if (jA >= 432){
        #pragma unroll
        for (int kk = 0; kk < 8; kk++) Ylds[(c8 + kk)*YL_STRIDE + q] = 0u;
      } else {
        int seg = jA / WIN;
        int spA = segbase[seg] + (jA - seg*WIN);
        const u16* ya = YS + ((size_t)(n*LL + spA))*256 + c8;
        uint4 va = *(const uint4*)ya;
        uint4 vb = *(const uint4*)(ya + 256);
        u32 pa[4] = {va.x, va.y, va.z, va.w};
        u32 pb[4] = {vb.x, vb.y, vb.z, vb.w};
        #pragma unroll
        for (int kk = 0; kk < 4; kk++){
          Ylds[(c8 + 2*kk    )*YL_STRIDE + q] = (pa[kk] & 0xffffu) | (pb[kk] << 16);
          Ylds[(c8 + 2*kk + 1)*YL_STRIDE + q] = (pa[kk] >> 16) | (pb[kk] & 0xffff0000u);
        }
      }
    }
    __syncthreads();
    bf16x8 ap[9];
    #pragma unroll
    for (int mt = 0; mt < 9; mt++)
      ap[mt] = *(const bf16x8*)&Plds[(mt*16 + row)*PL_STRIDE + j0 + kg*8];
    #pragma unroll
    for (int nt = 0; nt < 4; nt++){
      int co = (wave*4 + nt)*16 + row;
      bf16x8 bv = *(const bf16x8*)&Ylds[co*YL_STRIDE + kg*4];
      #pragma unroll
      for (int mt = 0; mt < 9; mt++)
        acc[mt][nt] = mfma16(ap[mt], bv, acc[mt][nt]);
    }
  }
  __syncthreads();
  // epilogue: stage rows, scatter to original positions (undo sort)
  u16* rstage = Plds;  // reuse as [144][264]
  #pragma unroll
  for (int mt = 0; mt < 9; mt++)
    #pragma unroll
    for (int nt = 0; nt < 4; nt++){
      int co = (wave*4 + nt)*16 + row;
      #pragma unroll
      for (int r = 0; r < 4; r++)
        rstage[(mt*16 + kg*4 + r)*264 + co] = f2bf(acc[mt][nt][r]);
    }
  __syncthreads();
  for (int q = t; q < WIN*32; q += 256){
    int rr2 = q >> 5, part = q & 31;
    uint4 v = *(const uint4*)&rstage[rr2*264 + part*8];
    *(uint4*)&RET[((size_t)(n*LL + (int)idxl[rr2]))*256 + part*8] = v;
  }
}

// ---------------- final: out = input + 0.1 * RET^T ----------------
__global__ void __launch_bounds__(256) k_final(const u16* __restrict__ RET,
    const float* __restrict__ x, float* __restrict__ out){
  __shared__ u16 tl[64][72];
  int n = blockIdx.z, cb = blockIdx.y * 64, l0 = blockIdx.x * 64;
  int t = threadIdx.x;
  for (int it = t; it < 512; it += 256){
    int r = it >> 3, part = it & 7;
    uint4 v = *(const uint4*)&RET[((size_t)(n*9216 + l0 + r))*256 + cb + part*8];
    *(uint4*)&tl[r][part*8] = v;
  }
  __syncthreads();
  int col = t >> 2, lq = (t & 3) * 16;
  int co = cb + col;
  const float* xin = x + ((size_t)(n*256 + co))*9216 + l0 + lq;
  float* op = out + ((size_t)(n*256 + co))*9216 + l0 + lq;
  #pragma unroll
  for (int i4 = 0; i4 < 4; i4++){
    float4 o4;
    o4.x = fmaf(bf2f(tl[lq + i4*4 + 0][col]), 0.1f, xin[i4*4 + 0]);
    o4.y = fmaf(bf2f(tl[lq + i4*4 + 1][col]), 0.1f, xin[i4*4 + 1]);
    o4.z = fmaf(bf2f(tl[lq + i4*4 + 2][col]), 0.1f, xin[i4*4 + 2]);
    o4.w = fmaf(bf2f(tl[lq + i4*4 + 3][col]), 0.1f, xin[i4*4 + 3]);
    *(float4*)&op[i4*4] = o4;
  }
}

// ---------------- workspace layout ----------------
#define OFF_XE   ((size_t)0)
#define SZ_XE    (8ull*9216*64*4)                 // 18874368
#define OFF_WF   (OFF_XE + SZ_XE)
#define SZ_WF    (9ull*8*64*32*2)                 // 294912
#define OFF_MT   (OFF_WF + SZ_WF)
#define SZ_MT    (64ull*128*4)                    // 32768
#define OFF_CODE (OFF_MT + SZ_MT)
#define SZ_CODE  (8ull*9216*4)                    // 294912
#define OFF_IDX  (OFF_CODE + SZ_CODE)
#define OFF_POS  (OFF_IDX + SZ_CODE)
#define OFF_XSN  (OFF_POS + SZ_CODE)
#define SZ_XSN   (8ull*9216*64*2)                 // 9437184
#define OFF_RNRM (OFF_XSN + SZ_XSN)
#define SZ_RNRM  (8ull*9216*4)                    // 294912
#define OFF_XTH  (OFF_RNRM + SZ_RNRM)
#define SZ_XTP   (8ull*8*98*98*32*2 + 32768)      // 39337984 + pad
#define OFF_XTL  (OFF_XTH + SZ_XTP)
// YS aliases XTH region, RET aliases XTL region (lifetimes disjoint):
// XT written by k_xt, read by k_conv3; YS written by k_conv1 (after conv3),
// RET written by k_attn (after conv1). Total = OFF_XTL + SZ_XTP ~= 103.5 MB.

extern "C" void kernel_launch(void* const* d_in, const int* in_sizes, int n_in,
                              void* d_out, int out_size, void* d_ws, size_t ws_size,
                              hipStream_t stream){
  const float* x     = (const float*)d_in[0];
  const float* means = (const float*)d_in[1];
  const float* wm    = (const float*)d_in[2];
  const float* bm    = (const float*)d_in[3];
  const float* wa    = (const float*)d_in[4];
  const float* ba    = (const float*)d_in[5];
  float* out = (float*)d_out;
  char* ws = (char*)d_ws;

  float* XE   = (float*)(ws + OFF_XE);
  u16*   WF16 = (u16*)(ws + OFF_WF);
  float* MT   = (float*)(ws + OFF_MT);
  u32*   CODE = (u32*)(ws + OFF_CODE);
  u32*   IDX  = (u32*)(ws + OFF_IDX);
  u32*   POS  = (u32*)(ws + OFF_POS);
  u16*   XSN  = (u16*)(ws + OFF_XSN);
  float* RNRM = (float*)(ws + OFF_RNRM);
  u16*   XTH  = (u16*)(ws + OFF_XTH);
  u16*   XTL  = (u16*)(ws + OFF_XTL);
  u16*   YS   = (u16*)(ws + OFF_XTH);   // alias
  u16*   RET  = (u16*)(ws + OFF_XTL);   // alias

  hipFuncSetAttribute((const void*)k_attn,
                      hipFuncAttributeMaxDynamicSharedMemorySize, SM_ATTN);

  k_prep <<<608, 256, 0, stream>>>(wm, means, WF16, MT);
  k_xt   <<<dim3(98, 8, 8), 256, 0, stream>>>(x, XTH, XTL);
  k_conv3<<<dim3(96, 8), 256, 0, stream>>>(XTH, XTL, WF16, bm, XE);
  k_dist <<<dim3(144, 8), 256, 0, stream>>>(XE, MT, CODE);
  k_sort <<<8, 256, 0, stream>>>(CODE, IDX, POS);
  k_conv1<<<dim3(144, 8), 256, 0, stream>>>(x, wa, ba, POS, YS);
  k_gx   <<<18432, 256, 0, stream>>>(XE, IDX, XSN, RNRM);
  k_attn <<<dim3(64, 8), 256, SM_ATTN, stream>>>(XSN, YS, IDX, RNRM, RET);
  k_final<<<dim3(144, 4, 8), 256, 0, stream>>>(RET, x, out);
}

// Round 5
// 513.176 us; speedup vs baseline: 2.3403x; 1.1267x over previous
//
#include <hip/hip_runtime.h>
#include <math.h>

typedef unsigned int u32;
typedef unsigned short u16;
typedef __bf16 bf16x8 __attribute__((ext_vector_type(8)));
typedef _Float16 f16x8 __attribute__((ext_vector_type(8)));
typedef float f32x4 __attribute__((ext_vector_type(4)));

#define LL 9216
#define WIN 144
#define NBK 64

__device__ __forceinline__ u16 f2bf(float f){
  union { float f; u32 u; } v; v.f = f;
  u32 u = v.u;
  return (u16)((u + 0x7fffu + ((u >> 16) & 1u)) >> 16);
}
__device__ __forceinline__ float bf2f(u16 b){
  union { u32 u; float f; } v; v.u = ((u32)b) << 16;
  return v.f;
}
__device__ __forceinline__ u16 f2h(float f){
  union { _Float16 h; u16 u; } v; v.h = (_Float16)f;
  return v.u;
}
__device__ __forceinline__ f32x4 mfma16(bf16x8 a, bf16x8 b, f32x4 c){
  return __builtin_amdgcn_mfma_f32_16x16x32_bf16(a, b, c, 0, 0, 0);
}
__device__ __forceinline__ f32x4 mfma16h(f16x8 a, f16x8 b, f32x4 c){
  return __builtin_amdgcn_mfma_f32_16x16x32_f16(a, b, c, 0, 0, 0);
}

// ---------------- prep: conv3 weights f16, means transpose, conv1 weights bf16 ----------------
// WF16 layout: [tap(9)][cc(8)][o(64)][ci(32)] f16
// WB  layout: [c8(32)][o(256)][8ci] bf16
__global__ void __launch_bounds__(256) k_prep(const float* __restrict__ wm,
    const float* __restrict__ means, const float* __restrict__ wa,
    u16* __restrict__ WF16, float* __restrict__ MT, u16* __restrict__ WB){
  int i = blockIdx.x * 256 + threadIdx.x;
  if (i < 9*8*64*32){
    int tap = i >> 14;
    int cc  = (i >> 11) & 7;
    int o   = (i >> 5) & 63;
    int chl = i & 31;
    WF16[i] = f2h(wm[(o*256 + cc*32 + chl)*9 + tap]);
  }
  int j = i - 9*8*64*32;
  if (j >= 0 && j < 64*128){
    int d = j >> 7, cl = j & 127;
    MT[j] = means[cl*64 + d];
  }
  int j2 = j - 64*128;
  if (j2 >= 0 && j2 < 32*256*8){
    int c8 = j2 >> 11;
    int rest = j2 & 2047;
    int o = rest >> 3, jj = rest & 7;
    WB[j2] = f2bf(wa[o*256 + c8*8 + jj]);
  }
}

// ---------------- transpose+pad+f16split+swizzle: x -> XTH/XTL ----------------
__global__ void __launch_bounds__(256) k_xt(const float* __restrict__ x,
    u16* __restrict__ XTH, u16* __restrict__ XTL){
  __shared__ float ls[32][97];
  int hh = blockIdx.x, cc = blockIdx.y, n = blockIdx.z;
  int t = threadIdx.x;
  int h = hh - 1;
  bool interior = (h >= 0 && h < 96);
  if (interior){
    int c = t >> 3, w0 = (t & 7) * 12;
    const float* src = x + ((size_t)(n*256 + cc*32 + c))*9216 + h*96 + w0;
    float4 v0 = *(const float4*)src;
    float4 v1 = *(const float4*)(src + 4);
    float4 v2 = *(const float4*)(src + 8);
    ls[c][w0+0]=v0.x; ls[c][w0+1]=v0.y; ls[c][w0+2]=v0.z; ls[c][w0+3]=v0.w;
    ls[c][w0+4]=v1.x; ls[c][w0+5]=v1.y; ls[c][w0+6]=v1.z; ls[c][w0+7]=v1.w;
    ls[c][w0+8]=v2.x; ls[c][w0+9]=v2.y; ls[c][w0+10]=v2.z; ls[c][w0+11]=v2.w;
  }
  __syncthreads();
  size_t base = ((size_t)((n*8 + cc)*98 + hh))*3136;
  for (int u = t; u < 392; u += 256){
    int ww = u >> 2, s = u & 3;
    int w = ww - 1;
    u16 hbuf[8], lbuf[8];
    if (interior && w >= 0 && w < 96){
      int f = (ww >> 1) & 3;
      int cbase = (s ^ f) * 8;
      #pragma unroll
      for (int j = 0; j < 8; j++){
        float v = ls[cbase + j][w];
        _Float16 hv = (_Float16)v;
        float lres = v - (float)hv;
        union { _Float16 h; u16 u; } uh; uh.h = hv;
        hbuf[j] = uh.u;
        lbuf[j] = f2h(lres);
      }
    } else {
      #pragma unroll
      for (int j = 0; j < 8; j++){ hbuf[j] = 0; lbuf[j] = 0; }
    }
    *(uint4*)&XTH[base + ww*32 + s*8] = *(const uint4*)hbuf;
    *(uint4*)&XTL[base + ww*32 + s*8] = *(const uint4*)lbuf;
  }
}

// ---------------- conv3x3 via MFMA (f16 split-2) -> XE fp32 ----------------
__global__ void __launch_bounds__(256) k_conv3(
    const u16* __restrict__ XTH, const u16* __restrict__ XTL,
    const u16* __restrict__ WF16, const float* __restrict__ bm,
    float* __restrict__ XE){
  __shared__ u16 AH[3*3136];
  __shared__ u16 AL[3*3136];
  int h0 = blockIdx.x, n = blockIdx.y;
  int t = threadIdx.x;
  int wave = t >> 6, lane = t & 63, row = lane & 15, kg = lane >> 4;
  f32x4 acc[6];
  #pragma unroll
  for (int m = 0; m < 6; m++){ acc[m][0]=0.f; acc[m][1]=0.f; acc[m][2]=0.f; acc[m][3]=0.f; }
  for (int cc = 0; cc < 8; cc++){
    __syncthreads();
    const u16* srcH = XTH + ((size_t)((n*8 + cc)*98 + h0))*3136;
    const u16* srcL = XTL + ((size_t)((n*8 + cc)*98 + h0))*3136;
    for (int u = t; u < 1176; u += 256){
      *(uint4*)&AH[u*8] = *(const uint4*)&srcH[u*8];
      *(uint4*)&AL[u*8] = *(const uint4*)&srcL[u*8];
    }
    __syncthreads();
    #pragma unroll
    for (int dy = 0; dy < 3; dy++){
      #pragma unroll
      for (int dx = 0; dx < 3; dx++){
        const u16* wp = WF16 + (((size_t)((dy*3 + dx)*8 + cc)*64) + wave*16 + row)*32 + kg*8;
        f16x8 bfrag = *(const f16x8*)wp;
        #pragma unroll
        for (int mt = 0; mt < 6; mt++){
          int ww = mt*16 + row + dx;
          int sl = (kg ^ ((ww >> 1) & 3)) * 8;
          f16x8 ahi = *(const f16x8*)&AH[dy*3136 + ww*32 + sl];
          f16x8 alo = *(const f16x8*)&AL[dy*3136 + ww*32 + sl];
          acc[mt] = mfma16h(ahi, bfrag, acc[mt]);
          acc[mt] = mfma16h(alo, bfrag, acc[mt]);
        }
      }
    }
  }
  int o = wave*16 + row;
  float bb = bm[o];
  #pragma unroll
  for (int mt = 0; mt < 6; mt++){
    #pragma unroll
    for (int r = 0; r < 4; r++){
      int m = mt*16 + kg*4 + r;
      XE[((size_t)(n*9216 + h0*96 + m))*64 + o] = acc[mt][r] + bb;
    }
  }
}

// ---------------- x -> XB bf16 [n][c8(32)][l(9216)][8ch] ----------------
__global__ void __launch_bounds__(256) k_xb(const float* __restrict__ x,
    u16* __restrict__ XB){
  int l = blockIdx.x * 256 + threadIdx.x;
  int c8 = blockIdx.y, n = blockIdx.z;
  const float* xp = x + ((size_t)(n*256 + c8*8))*9216 + l;
  u16 buf[8];
  #pragma unroll
  for (int j = 0; j < 8; j++) buf[j] = f2bf(xp[(size_t)j*9216]);
  *(uint4*)&XB[(((size_t)(n*32 + c8))*9216 + l)*8] = *(const uint4*)buf;
}

// ---------------- dists + argmax -> codes ----------------
__global__ void __launch_bounds__(256) k_dist(const float* __restrict__ XE,
    const float* __restrict__ MT, u32* __restrict__ CODE){
  __shared__ float ms[64][132];
  __shared__ float xsm[64][65];
  __shared__ float redv[64][16];
  __shared__ int  redi[64][16];
  int n = blockIdx.y, l0 = blockIdx.x * 64;
  int t = threadIdx.x;
  for (int e = t; e < 8192; e += 256) ms[e >> 7][e & 127] = MT[e];
  for (int e = t; e < 4096; e += 256)
    xsm[e >> 6][e & 63] = XE[((size_t)(n*9216 + l0 + (e >> 6)))*64 + (e & 63)];
  __syncthreads();
  int pg = t >> 4, cg = t & 15;
  int p0 = pg * 4, cl0 = cg * 8;
  float acc[4][8];
  #pragma unroll
  for (int i = 0; i < 4; i++)
    #pragma unroll
    for (int j = 0; j < 8; j++) acc[i][j] = 0.f;
  for (int d = 0; d < 64; d++){
    float4 m0 = *(const float4*)&ms[d][cl0];
    float4 m1 = *(const float4*)&ms[d][cl0 + 4];
    #pragma unroll
    for (int i = 0; i < 4; i++){
      float xv = xsm[p0 + i][d];
      acc[i][0] += xv * m0.x; acc[i][1] += xv * m0.y;
      acc[i][2] += xv * m0.z; acc[i][3] += xv * m0.w;
      acc[i][4] += xv * m1.x; acc[i][5] += xv * m1.y;
      acc[i][6] += xv * m1.z; acc[i][7] += xv * m1.w;
    }
  }
  #pragma unroll
  for (int i = 0; i < 4; i++){
    float bv = acc[i][0]; int bi = cl0;
    #pragma unroll
    for (int j = 1; j < 8; j++){ if (acc[i][j] > bv){ bv = acc[i][j]; bi = cl0 + j; } }
    redv[p0 + i][cg] = bv; redi[p0 + i][cg] = bi;
  }
  __syncthreads();
  if (t < 64){
    float bv = redv[t][0]; int bi = redi[t][0];
    for (int c = 1; c < 16; c++){
      float v = redv[t][c];
      if (v > bv){ bv = v; bi = redi[t][c]; }
    }
    CODE[n*9216 + l0 + t] = (u32)bi;
  }
}

// ---------------- stable counting sort per batch ----------------
__global__ void __launch_bounds__(256) k_sort(const u32* __restrict__ CODE,
    u32* __restrict__ IDX, u32* __restrict__ POS){
  __shared__ u32 hist[36][128];
  __shared__ u32 tot[128];
  __shared__ u32 whist[4][128];
  int n = blockIdx.x, t = threadIdx.x;
  for (int e = t; e < 36*128; e += 256) ((u32*)hist)[e] = 0;
  __syncthreads();
  for (int ch = 0; ch < 36; ch++){
    u32 c = CODE[n*9216 + ch*256 + t];
    atomicAdd(&hist[ch][c], 1u);
  }
  __syncthreads();
  if (t < 128){
    u32 run = 0;
    for (int ch = 0; ch < 36; ch++){ u32 v = hist[ch][t]; hist[ch][t] = run; run += v; }
    tot[t] = run;
  }
  __syncthreads();
  if (t == 0){
    u32 base = 0;
    for (int b = 0; b < 128; b++){ u32 v = tot[b]; tot[b] = base; base += v; }
  }
  __syncthreads();
  int wave = t >> 6, lane = t & 63;
  for (int ch = 0; ch < 36; ch++){
    for (int e = t; e < 512; e += 256) ((u32*)whist)[e] = 0;
    __syncthreads();
    int c = (int)CODE[n*9216 + ch*256 + t];
    atomicAdd(&whist[wave][c], 1u);
    __syncthreads();
    u32 pre = 0;
    for (int w2 = 0; w2 < wave; w2++) pre += whist[w2][c];
    u32 cnt = 0;
    for (int j = 0; j < 64; j++){
      int cj = __shfl(c, j, 64);
      cnt += (u32)((j < lane) && (cj == c));
    }
    u32 p = tot[c] + hist[ch][c] + pre + cnt;
    int l = ch*256 + t;
    IDX[n*9216 + p] = (u32)l;
    POS[n*9216 + l] = p;
    __syncthreads();
  }
}

// ---------------- conv1x1: zero-LDS register GEMM, scattered to sorted YS ----------------
__global__ void __launch_bounds__(256) k_conv1(const u16* __restrict__ XB,
    const u16* __restrict__ WB, const float* __restrict__ ba,
    const u32* __restrict__ POS, u16* __restrict__ YS){
  __shared__ u16 rl[64][264];
  __shared__ u32 posl[128];
  int n = blockIdx.y, l0 = blockIdx.x * 128;
  int t = threadIdx.x;
  int wv = t >> 6, lane = t & 63, row = lane & 15, kg = lane >> 4;
  if (t < 128) posl[t] = POS[n*9216 + l0 + t];
  f32x4 acc[8][4];
  #pragma unroll
  for (int a = 0; a < 8; a++)
    #pragma unroll
    for (int b = 0; b < 4; b++){ acc[a][b][0]=0.f; acc[a][b][1]=0.f; acc[a][b][2]=0.f; acc[a][b][3]=0.f; }
  const u16* xbase = XB + (((size_t)(n*32 + kg))*9216 + l0 + row)*8;
  const u16* wbase = WB + (((size_t)kg*256) + wv*64 + row)*8;
  for (int ks = 0; ks < 8; ks++){
    const u16* xp = xbase + (size_t)ks*4*9216*8;
    const u16* wp = wbase + (size_t)ks*4*256*8;
    bf16x8 a[8], b[4];
    #pragma unroll
    for (int mt = 0; mt < 8; mt++) a[mt] = *(const bf16x8*)(xp + mt*128);
    #pragma unroll
    for (int nt = 0; nt < 4; nt++) b[nt] = *(const bf16x8*)(wp + nt*128);
    #pragma unroll
    for (int nt = 0; nt < 4; nt++)
      #pragma unroll
      for (int mt = 0; mt < 8; mt++)
        acc[mt][nt] = mfma16(a[mt], b[nt], acc[mt][nt]);
  }
  float bb[4];
  #pragma unroll
  for (int nt = 0; nt < 4; nt++) bb[nt] = ba[wv*64 + nt*16 + row];
  #pragma unroll
  for (int half = 0; half < 2; half++){
    __syncthreads();
    #pragma unroll
    for (int m4 = 0; m4 < 4; m4++){
      #pragma unroll
      for (int nt = 0; nt < 4; nt++){
        int co = wv*64 + nt*16 + row;
        #pragma unroll
        for (int r = 0; r < 4; r++)
          rl[m4*16 + kg*4 + r][co] = f2bf(acc[half*4 + m4][nt][r] + bb[nt]);
      }
    }
    __syncthreads();
    for (int q = t; q < 2048; q += 256){
      int r = q >> 5, part = q & 31;
      uint4 v = *(const uint4*)&rl[r][part*8];
      *(uint4*)&YS[((size_t)(n*9216 + (int)posl[half*64 + r]))*256 + part*8] = v;
    }
  }
}

// ---------------- gather x rows into sorted order (normalized + norm) ----------------
__global__ void __launch_bounds__(256) k_gx(const float* __restrict__ XE,
    const u32* __restrict__ IDX, u16* __restrict__ XSN, float* __restrict__ RNRM){
  int gr = blockIdx.x * 4 + (threadIdx.x >> 6);
  int lane = threadIdx.x & 63;
  int n = gr / 9216;
  int l = (int)IDX[gr];
  float v = XE[((size_t)(n*9216 + l))*64 + lane];
  float s = v * v;
  #pragma unroll
  for (int m = 1; m < 64; m <<= 1) s += __shfl_xor(s, m, 64);
  float denom = fmaxf(sqrtf(s), 5e-5f);
  XSN[(size_t)gr*64 + lane] = f2bf(v / denom);
  if (lane == 0) RNRM[gr] = denom;
}

// ---------------- attention per (n, window) ----------------
#define PL_STRIDE 456
#define SM_YLDS (144*456*2)
#define YL_STRIDE 20
#define SM_IDXL (SM_YLDS + 256*YL_STRIDE*4)
#define SM_ATTN (SM_IDXL + 144*4)

__global__ void __launch_bounds__(256, 1) k_attn(const u16* __restrict__ XSN,
    const u16* __restrict__ YS, const u32* __restrict__ IDX,
    const float* __restrict__ RNRM, u16* __restrict__ RET){
  extern __shared__ char smem[];
  u16* Plds = (u16*)smem;
  u32* Ylds = (u32*)(smem + SM_YLDS);
  u32* idxl = (u32*)(smem + SM_IDXL);
  int n = blockIdx.y, kw = blockIdx.x;
  int t = threadIdx.x;
  int wave = t >> 6, lane = t & 63;
  int row = lane & 15, kg = lane >> 4;
  int p0 = kw * WIN;
  if (t < WIN) idxl[t] = IDX[n*LL + p0 + t];
  int wprev = (kw + NBK - 1) & (NBK - 1), wnext = (kw + 1) & (NBK - 1);
  int segbase[3] = { p0, wprev*WIN, wnext*WIN };
  // S = xb_normalized @ x_match^T   (store unit-scale logits bf16 to Plds)
  {
    bf16x8 a[9][2];
    #pragma unroll
    for (int mt = 0; mt < 9; mt++){
      const u16* xp = XSN + ((size_t)(n*LL + p0 + mt*16 + row))*64 + kg*8;
      a[mt][0] = *(const bf16x8*)xp;
      a[mt][1] = *(const bf16x8*)(xp + 32);
    }
    for (int jt = wave; jt < 27; jt += 4){
      int j0 = jt * 16;
      int seg = j0 / WIN;
      int sp = segbase[seg] + (j0 - seg*WIN) + row;
      const u16* bp = XSN + ((size_t)(n*LL + sp))*64 + kg*8;
      bf16x8 b0 = *(const bf16x8*)bp;
      bf16x8 b1 = *(const bf16x8*)(bp + 32);
      #pragma unroll
      for (int mt = 0; mt < 9; mt++){
        f32x4 s; s[0]=0.f; s[1]=0.f; s[2]=0.f; s[3]=0.f;
        s = mfma16(a[mt][0], b0, s);
        s = mfma16(a[mt][1], b1, s);
        #pragma unroll
        for (int r = 0; r < 4; r++)
          Plds[(mt*16 + kg*4 + r)*PL_STRIDE + j0 + row] = f2bf(s[r]);
      }
    }
  }
  __syncthreads();
  // exact softmax per row (16 threads per row), logits scaled by row norm
  for (int pass = 0; pass < 9; pass++){
    int rr = pass*16 + (t >> 4);
    int tc = t & 15;
    float rn = RNRM[n*LL + p0 + rr];
    u16* prow = Plds + rr*PL_STRIDE;
    float vals[27]; float mx = -1e30f;
    #pragma unroll
    for (int jj = 0; jj < 27; jj++){ vals[jj] = bf2f(prow[tc + 16*jj]) * rn; mx = fmaxf(mx, vals[jj]); }
    mx = fmaxf(mx, __shfl_xor(mx, 1, 64));
    mx = fmaxf(mx, __shfl_xor(mx, 2, 64));
    mx = fmaxf(mx, __shfl_xor(mx, 4, 64));
    mx = fmaxf(mx, __shfl_xor(mx, 8, 64));
    float sum = 0.f;
    #pragma unroll
    for (int jj = 0; jj < 27; jj++){ vals[jj] = __expf(vals[jj] - mx); sum += vals[jj]; }
    sum += __shfl_xor(sum, 1, 64);
    sum += __shfl_xor(sum, 2, 64);
    sum += __shfl_xor(sum, 4, 64);
    sum += __shfl_xor(sum, 8, 64);
    float inv = 1.f / sum;
    #pragma unroll
    for (int jj = 0; jj < 27; jj++) prow[tc + 16*jj] = f2bf(vals[jj] * inv);
    if (tc < 12){ prow[432 + tc] = 0; prow[444 + tc] = 0; }
  }
  __syncthreads();
  // PV: ret = P @ Y3
  f32x4 acc[9][4];
  #pragma unroll
  for (int a = 0; a < 9; a++)
    #pragma unroll
    for (int b = 0; b < 4; b++){ acc[a][b][0]=0.f; acc[a][b][1]=0.f; acc[a][b][2]=0.f; acc[a][b][3]=0.f; }
  for (int ks = 0; ks < 14; ks++){
    int j0 = ks * 32;
    __syncthreads();
    for (int it = t; it < 512; it += 256){
      int q = it & 15;
      int c8 = (it >> 4) * 8;
      int jA = j0 + 2*q;
      if (jA >= 432){
        #pragma unroll
        for (int kk = 0; kk < 8; kk++) Ylds[(c8 + kk)*YL_STRIDE + q] = 0u;
      } else {
        int seg = jA / WIN;
        int spA = segbase[seg] + (jA - seg*WIN);
        const u16* ya = YS + ((size_t)(n*LL + spA))*256 + c8;
        uint4 va = *(const uint4*)ya;
        uint4 vb = *(const uint4*)(ya + 256);
        u32 pa[4] = {va.x, va.y, va.z, va.w};
        u32 pb[4] = {vb.x, vb.y, vb.z, vb.w};
        #pragma unroll
        for (int kk = 0; kk < 4; kk++){
          Ylds[(c8 + 2*kk    )*YL_STRIDE + q] = (pa[kk] & 0xffffu) | (pb[kk] << 16);
          Ylds[(c8 + 2*kk + 1)*YL_STRIDE + q] = (pa[kk] >> 16) | (pb[kk] & 0xffff0000u);
        }
      }
    }
    __syncthreads();
    bf16x8 ap[9];
    #pragma unroll
    for (int mt = 0; mt < 9; mt++)
      ap[mt] = *(const bf16x8*)&Plds[(mt*16 + row)*PL_STRIDE + j0 + kg*8];
    #pragma unroll
    for (int nt = 0; nt < 4; nt++){
      int co = (wave*4 + nt)*16 + row;
      bf16x8 bv = *(const bf16x8*)&Ylds[co*YL_STRIDE + kg*4];
      #pragma unroll
      for (int mt = 0; mt < 9; mt++)
        acc[mt][nt] = mfma16(ap[mt], bv, acc[mt][nt]);
    }
  }
  __syncthreads();
  // epilogue: stage rows, scatter to original positions (undo sort)
  u16* rstage = Plds;  // reuse as [144][264]
  #pragma unroll
  for (int mt = 0; mt < 9; mt++)
    #pragma unroll
    for (int nt = 0; nt < 4; nt++){
      int co = (wave*4 + nt)*16 + row;
      #pragma unroll
      for (int r = 0; r < 4; r++)
        rstage[(mt*16 + kg*4 + r)*264 + co] = f2bf(acc[mt][nt][r]);
    }
  __syncthreads();
  for (int q = t; q < WIN*32; q += 256){
    int rr2 = q >> 5, part = q & 31;
    uint4 v = *(const uint4*)&rstage[rr2*264 + part*8];
    *(uint4*)&RET[((size_t)(n*LL + (int)idxl[rr2]))*256 + part*8] = v;
  }
}

// ---------------- final: out = input + 0.1 * RET^T ----------------
__global__ void __launch_bounds__(256) k_final(const u16* __restrict__ RET,
    const float* __restrict__ x, float* __restrict__ out){
  __shared__ u16 tl[64][72];
  int n = blockIdx.z, cb = blockIdx.y * 64, l0 = blockIdx.x * 64;
  int t = threadIdx.x;
  for (int it = t; it < 512; it += 256){
    int r = it >> 3, part = it & 7;
    uint4 v = *(const uint4*)&RET[((size_t)(n*9216 + l0 + r))*256 + cb + part*8];
    *(uint4*)&tl[r][part*8] = v;
  }
  __syncthreads();
  int col = t >> 2, lq = (t & 3) * 16;
  int co = cb + col;
  const float* xin = x + ((size_t)(n*256 + co))*9216 + l0 + lq;
  float* op = out + ((size_t)(n*256 + co))*9216 + l0 + lq;
  #pragma unroll
  for (int i4 = 0; i4 < 4; i4++){
    float4 o4;
    o4.x = fmaf(bf2f(tl[lq + i4*4 + 0][col]), 0.1f, xin[i4*4 + 0]);
    o4.y = fmaf(bf2f(tl[lq + i4*4 + 1][col]), 0.1f, xin[i4*4 + 1]);
    o4.z = fmaf(bf2f(tl[lq + i4*4 + 2][col]), 0.1f, xin[i4*4 + 2]);
    o4.w = fmaf(bf2f(tl[lq + i4*4 + 3][col]), 0.1f, xin[i4*4 + 3]);
    *(float4*)&op[i4*4] = o4;
  }
}

// ---------------- workspace layout ----------------
#define OFF_XE   ((size_t)0)
#define SZ_XE    (8ull*9216*64*4)                 // 18874368
#define OFF_WF   (OFF_XE + SZ_XE)
#define SZ_WF    (9ull*8*64*32*2)                 // 294912
#define OFF_MT   (OFF_WF + SZ_WF)
#define SZ_MT    (64ull*128*4)                    // 32768
#define OFF_WB   (OFF_MT + SZ_MT)
#define SZ_WB    (32ull*256*8*2)                  // 131072
#define OFF_CODE (OFF_WB + SZ_WB)
#define SZ_CODE  (8ull*9216*4)                    // 294912
#define OFF_IDX  (OFF_CODE + SZ_CODE)
#define OFF_POS  (OFF_IDX + SZ_CODE)
#define OFF_XSN  (OFF_POS + SZ_CODE)
#define SZ_XSN   (8ull*9216*64*2)                 // 9437184
#define OFF_RNRM (OFF_XSN + SZ_XSN)
#define SZ_RNRM  (8ull*9216*4)                    // 294912
#define OFF_XTH  (OFF_RNRM + SZ_RNRM)
#define SZ_XTP   (8ull*8*98*98*32*2 + 32768)      // 39337984 + pad
#define OFF_XTL  (OFF_XTH + SZ_XTP)
// Aliases (lifetimes disjoint):
//   YS  @ OFF_XTH : conv3 reads XTH before conv1 writes YS; attn reads YS.
//   XB  @ OFF_XTL : k_xb writes after conv3 reads XTL; conv1 reads XB.
//   RET @ OFF_XTL : attn writes after conv1 consumed XB; final reads RET.

extern "C" void kernel_launch(void* const* d_in, const int* in_sizes, int n_in,
                              void* d_out, int out_size, void* d_ws, size_t ws_size,
                              hipStream_t stream){
  const float* x     = (const float*)d_in[0];
  const float* means = (const float*)d_in[1];
  const float* wm    = (const float*)d_in[2];
  const float* bm    = (const float*)d_in[3];
  const float* wa    = (const float*)d_in[4];
  const float* ba    = (const float*)d_in[5];
  float* out = (float*)d_out;
  char* ws = (char*)d_ws;

  float* XE   = (float*)(ws + OFF_XE);
  u16*   WF16 = (u16*)(ws + OFF_WF);
  float* MT   = (float*)(ws + OFF_MT);
  u16*   WB   = (u16*)(ws + OFF_WB);
  u32*   CODE = (u32*)(ws + OFF_CODE);
  u32*   IDX  = (u32*)(ws + OFF_IDX);
  u32*   POS  = (u32*)(ws + OFF_POS);
  u16*   XSN  = (u16*)(ws + OFF_XSN);
  float* RNRM = (float*)(ws + OFF_RNRM);
  u16*   XTH  = (u16*)(ws + OFF_XTH);
  u16*   XTL  = (u16*)(ws + OFF_XTL);
  u16*   YS   = (u16*)(ws + OFF_XTH);   // alias
  u16*   XB   = (u16*)(ws + OFF_XTL);   // alias
  u16*   RET  = (u16*)(ws + OFF_XTL);   // alias

  hipFuncSetAttribute((const void*)k_attn,
                      hipFuncAttributeMaxDynamicSharedMemorySize, SM_ATTN);

  k_prep <<<864, 256, 0, stream>>>(wm, means, wa, WF16, MT, WB);
  k_xt   <<<dim3(98, 8, 8), 256, 0, stream>>>(x, XTH, XTL);
  k_conv3<<<dim3(96, 8), 256, 0, stream>>>(XTH, XTL, WF16, bm, XE);
  k_xb   <<<dim3(36, 32, 8), 256, 0, stream>>>(x, XB);
  k_dist <<<dim3(144, 8), 256, 0, stream>>>(XE, MT, CODE);
  k_sort <<<8, 256, 0, stream>>>(CODE, IDX, POS);
  k_conv1<<<dim3(72, 8), 256, 0, stream>>>(XB, WB, ba, POS, YS);
  k_gx   <<<18432, 256, 0, stream>>>(XE, IDX, XSN, RNRM);
  k_attn <<<dim3(64, 8), 256, SM_ATTN, stream>>>(XSN, YS, IDX, RNRM, RET);
  k_final<<<dim3(144, 4, 8), 256, 0, stream>>>(RET, x, out);
}